// Round 1
// baseline (167.805 us; speedup 1.0000x reference)
//
#include <hip/hip_runtime.h>

#define NCOL 152   // 151 real output columns + 1 zero pad
#define NROW 58    // 57 weight rows + 1 bias row
#define KC   8     // k-chunks in collapse GEMM
#define KLEN 256   // 2048 / KC

// output region offsets (flat concat: pose, cam, phi, leaf, shape)
#define POSE_OFF  0
#define CAM_OFF   589824
#define PHI_OFF   614400
#define LEAF_OFF  991232
#define SHAPE_OFF 1155072

__constant__ int c_NEB1[24] = {17,11,12,17,13,14,17,15,16,18,15,16,18,18,18,18,5,6,7,8,9,10,9,10};
__constant__ int c_NEB2[24] = {18,17,17,18,11,12,18,13,14,17,13,14,0,5,6,0,18,18,5,6,7,8,7,8};

// ---------------------------------------------------------------------------
// K1: partial collapse GEMM.  partial[r][kc][c] = sum_{k in chunk} A[r][k]*src[k][c]
// A rows: r<57 -> W_enc row r ; r==57 -> b_enc.
// src columns: concatenated [W_shape | W_cam | W_phi | W_leaf | Rf(j,:,o)].
// ---------------------------------------------------------------------------
__global__ __launch_bounds__(192) void k_collapse(
    const float* __restrict__ W_enc, const float* __restrict__ b_enc,
    const float* __restrict__ W_shape, const float* __restrict__ W_cam,
    const float* __restrict__ W_phi, const float* __restrict__ W_leaf,
    const float* __restrict__ Rf, float* __restrict__ partial) {
  int c = threadIdx.x;
  if (c >= NCOL) return;
  int kc = blockIdx.x;   // 0..7
  int rg = blockIdx.y;   // 0..14  (4 rows each)

  const float* base; int stride; bool valid = true;
  if (c < 10)       { base = W_shape + c;      stride = 10; }
  else if (c < 13)  { base = W_cam  + (c-10);  stride = 3;  }
  else if (c < 59)  { base = W_phi  + (c-13);  stride = 46; }
  else if (c < 79)  { base = W_leaf + (c-59);  stride = 20; }
  else if (c < 151) { int p = c-79; base = Rf + (p/3)*6144 + (p%3); stride = 3; }
  else              { base = W_shape; stride = 0; valid = false; }

  int r0 = rg*4;
  const float* a0 = (r0+0 < 57) ? (W_enc + (r0+0)*2048) : b_enc;
  const float* a1 = (r0+1 < 57) ? (W_enc + (r0+1)*2048) : b_enc;
  const float* a2 = (r0+2 < 57) ? (W_enc + (r0+2)*2048) : b_enc;
  const float* a3 = (r0+3 < 57) ? (W_enc + (r0+3)*2048) : b_enc;

  float acc0=0.f, acc1=0.f, acc2=0.f, acc3=0.f;
  int k0 = kc*KLEN;
  #pragma unroll 4
  for (int k = k0; k < k0 + KLEN; ++k) {
    float v = base[(size_t)k * (size_t)stride];
    acc0 += a0[k]*v; acc1 += a1[k]*v; acc2 += a2[k]*v; acc3 += a3[k]*v;
  }
  if (!valid) { acc0 = acc1 = acc2 = acc3 = 0.f; }

  if (r0+0 < NROW) partial[((r0+0)*KC + kc)*NCOL + c] = acc0;
  if (r0+1 < NROW) partial[((r0+1)*KC + kc)*NCOL + c] = acc1;
  if (r0+2 < NROW) partial[((r0+2)*KC + kc)*NCOL + c] = acc2;
  if (r0+3 < NROW) partial[((r0+3)*KC + kc)*NCOL + c] = acc3;
}

// ---------------------------------------------------------------------------
// K2: per output-row r: sum k-chunk partials, add bias/init terms (row 57),
// fold M1[j]=L1_w[j]@R1[j] and M2[j]=L2_w[j]@R2[j] into the matching rows,
// then subtract the j=0 pose column from all pose columns. Write Cfull[58][152].
// ---------------------------------------------------------------------------
__global__ __launch_bounds__(192) void k_finalize(
    const float* __restrict__ partial,
    const float* __restrict__ b_shape, const float* __restrict__ b_cam,
    const float* __restrict__ b_phi, const float* __restrict__ b_leaf,
    const float* __restrict__ init_shape, const float* __restrict__ init_cam,
    const float* __restrict__ L1_w, const float* __restrict__ L1_b,
    const float* __restrict__ L2_w, const float* __restrict__ L2_b,
    const float* __restrict__ R1, const float* __restrict__ R2,
    const float* __restrict__ reg_b, float* __restrict__ Cfull) {
  __shared__ float sbase[NCOL];
  int r = blockIdx.x;       // 0..57
  int t = threadIdx.x;      // 0..191

  if (t < NCOL) {
    float s = 0.f;
    #pragma unroll
    for (int kc = 0; kc < KC; ++kc) s += partial[(r*KC + kc)*NCOL + t];
    if (r == 57) {  // constant bias terms
      int c = t;
      if (c < 10)       s += b_shape[c] + init_shape[c];
      else if (c < 13)  s += b_cam[c-10] + init_cam[c-10];
      else if (c < 59)  s += b_phi[c-13];
      else if (c < 79)  s += b_leaf[c-59];
      else if (c < 151) s += reg_b[c-79];
    }
    sbase[t] = s;
  }
  __syncthreads();

  // M-folds: thread t -> (j, m, o). For r<57 only joints with NEB_m[j]==r/3.
  if (t < 144) {
    int j = t / 6, q = t % 6, m = q / 3, o = q % 3;
    bool doit;
    const float* Lvec;
    if (r < 57) {
      int jr = r / 3, d = r % 3;
      int nb = (m == 0) ? c_NEB1[j] : c_NEB2[j];
      doit = (nb == jr);
      Lvec = ((m == 0) ? L1_w : L2_w) + j*1536 + d*512;
    } else {
      doit = true;  // bias row: L*_b[j] @ R*[j]
      Lvec = ((m == 0) ? L1_b : L2_b) + j*512;
    }
    if (doit) {
      const float* Rm = ((m == 0) ? R1 : R2) + j*1536 + o;
      float s = 0.f;
      #pragma unroll 4
      for (int h = 0; h < 512; ++h) s += Lvec[h] * Rm[h*3];
      atomicAdd(&sbase[79 + 3*j + o], s);
    }
  }
  __syncthreads();

  float v0 = sbase[79], v1 = sbase[80], v2 = sbase[81];
  if (t < NCOL) {
    float s = sbase[t];
    if (t >= 79 && t < 151) {   // pred_pose = pose - pose[:, 0]
      int o = (t - 79) % 3;
      s -= (o == 0) ? v0 : ((o == 1) ? v1 : v2);
    }
    Cfull[r*NCOL + t] = s;
  }
}

// ---------------------------------------------------------------------------
// K3: out[b, 0:151] = x[b, 0:57] @ Cfull[0:57] + Cfull[57], scattered into the
// 5 output regions. Wave handles 4 rows; lane l owns cols (2l,2l+1) and
// (128+2l, 129+2l). Cfull staged in LDS.
// ---------------------------------------------------------------------------
__device__ __forceinline__ void store_col(float* __restrict__ out, int b, int c, float v) {
  if (c < 10)       out[SHAPE_OFF + b*10 + c]      = v;
  else if (c < 13)  out[CAM_OFF   + b*3  + (c-10)] = v;
  else if (c < 59)  out[PHI_OFF   + b*46 + (c-13)] = v;
  else if (c < 79)  out[LEAF_OFF  + b*20 + (c-59)] = v;
  else              out[POSE_OFF  + b*72 + (c-79)] = v;
}

__global__ __launch_bounds__(256) void k_main(
    const float* __restrict__ joints, const float* __restrict__ Cfull,
    float* __restrict__ out) {
  __shared__ float C[NROW * NCOL];   // 8816 floats = 35264 B
  for (int i = threadIdx.x; i < (NROW*NCOL)/4; i += 256)
    ((float4*)C)[i] = ((const float4*)Cfull)[i];
  __syncthreads();

  int w = __builtin_amdgcn_readfirstlane((int)(threadIdx.x >> 6));
  int l = (int)(threadIdx.x & 63);
  int b0 = blockIdx.x * 16 + w * 4;

  const float* x0 = joints + (size_t)b0 * 57;  // wave-uniform -> s_loads
  const float* x1 = x0 + 57;
  const float* x2 = x1 + 57;
  const float* x3 = x2 + 57;

  int lc = (l < 12) ? (2*l) : 22;  // clamp second-slot LDS addr in-bounds

  float acc[4][4] = {};
  #pragma unroll
  for (int r = 0; r < 58; ++r) {
    float2 p0 = *(const float2*)&C[r*NCOL + 2*l];
    float2 p1 = *(const float2*)&C[r*NCOL + 128 + lc];
    float xr;
    xr = (r < 57) ? x0[r] : 1.f;
    acc[0][0] += xr*p0.x; acc[0][1] += xr*p0.y; acc[0][2] += xr*p1.x; acc[0][3] += xr*p1.y;
    xr = (r < 57) ? x1[r] : 1.f;
    acc[1][0] += xr*p0.x; acc[1][1] += xr*p0.y; acc[1][2] += xr*p1.x; acc[1][3] += xr*p1.y;
    xr = (r < 57) ? x2[r] : 1.f;
    acc[2][0] += xr*p0.x; acc[2][1] += xr*p0.y; acc[2][2] += xr*p1.x; acc[2][3] += xr*p1.y;
    xr = (r < 57) ? x3[r] : 1.f;
    acc[3][0] += xr*p0.x; acc[3][1] += xr*p0.y; acc[3][2] += xr*p1.x; acc[3][3] += xr*p1.y;
  }

  #pragma unroll
  for (int i = 0; i < 4; ++i) {
    int b = b0 + i;
    store_col(out, b, 2*l,     acc[i][0]);
    store_col(out, b, 2*l + 1, acc[i][1]);
    if (l < 12) {
      store_col(out, b, 128 + 2*l, acc[i][2]);
      if (l < 11) store_col(out, b, 129 + 2*l, acc[i][3]);  // col 151 is pad
    }
  }
}

extern "C" void kernel_launch(void* const* d_in, const int* in_sizes, int n_in,
                              void* d_out, int out_size, void* d_ws, size_t ws_size,
                              hipStream_t stream) {
  const float* joints     = (const float*)d_in[0];
  const float* W_enc      = (const float*)d_in[1];
  const float* b_enc      = (const float*)d_in[2];
  const float* W_shape    = (const float*)d_in[3];
  const float* b_shape    = (const float*)d_in[4];
  const float* W_cam      = (const float*)d_in[5];
  const float* b_cam      = (const float*)d_in[6];
  const float* W_phi      = (const float*)d_in[7];
  const float* b_phi      = (const float*)d_in[8];
  const float* W_leaf     = (const float*)d_in[9];
  const float* b_leaf     = (const float*)d_in[10];
  const float* init_shape = (const float*)d_in[11];
  const float* init_cam   = (const float*)d_in[12];
  const float* L1_w       = (const float*)d_in[13];
  const float* L1_b       = (const float*)d_in[14];
  const float* L2_w       = (const float*)d_in[15];
  const float* L2_b       = (const float*)d_in[16];
  const float* Rf         = (const float*)d_in[17];
  const float* R1         = (const float*)d_in[18];
  const float* R2         = (const float*)d_in[19];
  const float* reg_b      = (const float*)d_in[20];

  float* partial = (float*)d_ws;                                       // 58*8*152 f32
  float* Cfull   = (float*)((char*)d_ws + NROW*KC*NCOL*sizeof(float)); // 58*152 f32
  float* outp    = (float*)d_out;

  hipLaunchKernelGGL(k_collapse, dim3(KC, 15), dim3(192), 0, stream,
                     W_enc, b_enc, W_shape, W_cam, W_phi, W_leaf, Rf, partial);
  hipLaunchKernelGGL(k_finalize, dim3(NROW), dim3(192), 0, stream,
                     partial, b_shape, b_cam, b_phi, b_leaf, init_shape, init_cam,
                     L1_w, L1_b, L2_w, L2_b, R1, R2, reg_b, Cfull);
  hipLaunchKernelGGL(k_main, dim3(512), dim3(256), 0, stream,
                     joints, Cfull, outp);
}

// Round 2
// 120.141 us; speedup vs baseline: 1.3967x; 1.3967x over previous
//
#include <hip/hip_runtime.h>

#define NCOL 152   // 151 real output columns + 1 zero pad
#define NROW 58    // 57 weight rows + 1 bias row
#define KC   16    // k-chunks in collapse GEMM
#define KLEN 128   // 2048 / KC
#define NCOLL_BLK (KC * 15)   // 240 collapse-role blocks

// output region offsets (flat concat: pose, cam, phi, leaf, shape)
#define POSE_OFF  0
#define CAM_OFF   589824
#define PHI_OFF   614400
#define LEAF_OFF  991232
#define SHAPE_OFF 1155072

__constant__ int c_NEB1[24] = {17,11,12,17,13,14,17,15,16,18,15,16,18,18,18,18,5,6,7,8,9,10,9,10};
__constant__ int c_NEB2[24] = {18,17,17,18,11,12,18,13,14,17,13,14,0,5,6,0,18,18,5,6,7,8,7,8};

// ---------------------------------------------------------------------------
// K1 (fused, two block roles):
//  blocks [0, 240):  partial collapse GEMM
//     partial[r][kc][c] = sum_{k in chunk kc} A[r][k] * src[k][c]
//     A rows: r<57 -> W_enc row r ; r==57 -> b_enc.
//     src cols: [W_shape | W_cam | W_phi | W_leaf | Rf(j,:,o)].
//  blocks [240, 288): matrix folds, one block per (j,m):
//     mfold[jm][d*3+o] = sum_h Lm_w[j][d][h] * Rm[j][h][o]   (d,o in 0..2)
//     mfold[jm][9+o]   = sum_h Lm_b[j][h]    * Rm[j][h][o]
// ---------------------------------------------------------------------------
__global__ __launch_bounds__(256) void k_stage1(
    const float* __restrict__ W_enc, const float* __restrict__ b_enc,
    const float* __restrict__ W_shape, const float* __restrict__ W_cam,
    const float* __restrict__ W_phi, const float* __restrict__ W_leaf,
    const float* __restrict__ Rf,
    const float* __restrict__ L1_w, const float* __restrict__ L1_b,
    const float* __restrict__ L2_w, const float* __restrict__ L2_b,
    const float* __restrict__ R1, const float* __restrict__ R2,
    float* __restrict__ partial, float* __restrict__ mfold) {
  __shared__ float sred[4 * 12];
  int bid = blockIdx.x;

  if (bid < NCOLL_BLK) {
    // ---- collapse role ----
    int c = threadIdx.x;
    if (c >= NCOL) return;
    int kc = bid & (KC - 1);
    int rg = bid >> 4;           // 0..14, 4 rows each

    const float* base; int stride; bool valid = true;
    if (c < 10)       { base = W_shape + c;      stride = 10; }
    else if (c < 13)  { base = W_cam  + (c-10);  stride = 3;  }
    else if (c < 59)  { base = W_phi  + (c-13);  stride = 46; }
    else if (c < 79)  { base = W_leaf + (c-59);  stride = 20; }
    else if (c < 151) { int p = c-79; base = Rf + (p/3)*6144 + (p%3); stride = 3; }
    else              { base = W_shape; stride = 0; valid = false; }

    int r0 = rg * 4;
    const float* a0 = (r0+0 < 57) ? (W_enc + (r0+0)*2048) : b_enc;
    const float* a1 = (r0+1 < 57) ? (W_enc + (r0+1)*2048) : b_enc;
    const float* a2 = (r0+2 < 57) ? (W_enc + (r0+2)*2048) : b_enc;
    const float* a3 = (r0+3 < 57) ? (W_enc + (r0+3)*2048) : b_enc;

    float acc0=0.f, acc1=0.f, acc2=0.f, acc3=0.f;
    int k0 = kc * KLEN;
    #pragma unroll 8
    for (int k = k0; k < k0 + KLEN; ++k) {
      float v = base[(size_t)k * (size_t)stride];
      acc0 += a0[k]*v; acc1 += a1[k]*v; acc2 += a2[k]*v; acc3 += a3[k]*v;
    }
    if (!valid) { acc0 = acc1 = acc2 = acc3 = 0.f; }

    if (r0+0 < NROW) partial[((r0+0)*KC + kc)*NCOL + c] = acc0;
    if (r0+1 < NROW) partial[((r0+1)*KC + kc)*NCOL + c] = acc1;
    if (r0+2 < NROW) partial[((r0+2)*KC + kc)*NCOL + c] = acc2;
    if (r0+3 < NROW) partial[((r0+3)*KC + kc)*NCOL + c] = acc3;
    return;
  }

  // ---- mfold role ----
  int jm = bid - NCOLL_BLK;          // 0..47
  int j = jm >> 1, m = jm & 1;
  const float* Lw = (m == 0) ? L1_w : L2_w;   // (SJ,3,H)
  const float* Lb = (m == 0) ? L1_b : L2_b;   // (SJ,H)
  const float* Rm = (m == 0) ? R1   : R2;     // (SJ,H,3)

  int t = threadIdx.x;
  float acc[12];
  #pragma unroll
  for (int q = 0; q < 12; ++q) acc[q] = 0.f;

  #pragma unroll
  for (int hh = 0; hh < 2; ++hh) {
    int h = t + hh * 256;
    float l0 = Lw[j*1536 + 0*512 + h];
    float l1 = Lw[j*1536 + 1*512 + h];
    float l2 = Lw[j*1536 + 2*512 + h];
    float lb = Lb[j*512 + h];
    float r0 = Rm[j*1536 + h*3 + 0];
    float r1 = Rm[j*1536 + h*3 + 1];
    float r2 = Rm[j*1536 + h*3 + 2];
    acc[0] += l0*r0; acc[1] += l0*r1; acc[2]  += l0*r2;
    acc[3] += l1*r0; acc[4] += l1*r1; acc[5]  += l1*r2;
    acc[6] += l2*r0; acc[7] += l2*r1; acc[8]  += l2*r2;
    acc[9] += lb*r0; acc[10]+= lb*r1; acc[11] += lb*r2;
  }

  // wave reduce (64 lanes), then cross-wave via LDS
  #pragma unroll
  for (int q = 0; q < 12; ++q) {
    float v = acc[q];
    v += __shfl_down(v, 32);
    v += __shfl_down(v, 16);
    v += __shfl_down(v, 8);
    v += __shfl_down(v, 4);
    v += __shfl_down(v, 2);
    v += __shfl_down(v, 1);
    acc[q] = v;
  }
  int wv = t >> 6, ln = t & 63;
  if (ln == 0) {
    #pragma unroll
    for (int q = 0; q < 12; ++q) sred[wv*12 + q] = acc[q];
  }
  __syncthreads();
  if (t < 12)
    mfold[jm*12 + t] = sred[0*12 + t] + sred[1*12 + t] + sred[2*12 + t] + sred[3*12 + t];
}

// ---------------------------------------------------------------------------
// K2: per output-row r: sum the KC partials, add bias/init terms (row 57),
// add the precomputed mfold entries into the matching pose columns, then
// subtract the j=0 pose column from all pose columns. Write Cfull[58][152].
// ---------------------------------------------------------------------------
__global__ __launch_bounds__(192) void k_finalize(
    const float* __restrict__ partial, const float* __restrict__ mfold,
    const float* __restrict__ b_shape, const float* __restrict__ b_cam,
    const float* __restrict__ b_phi, const float* __restrict__ b_leaf,
    const float* __restrict__ init_shape, const float* __restrict__ init_cam,
    const float* __restrict__ reg_b, float* __restrict__ Cfull) {
  __shared__ float sbase[NCOL];
  int r = blockIdx.x;       // 0..57
  int t = threadIdx.x;      // 0..191

  if (t < NCOL) {
    float s = 0.f;
    #pragma unroll
    for (int kc = 0; kc < KC; ++kc) s += partial[(r*KC + kc)*NCOL + t];

    if (r == 57) {  // constant bias terms
      int c = t;
      if (c < 10)       s += b_shape[c] + init_shape[c];
      else if (c < 13)  s += b_cam[c-10] + init_cam[c-10];
      else if (c < 59)  s += b_phi[c-13];
      else if (c < 79)  s += b_leaf[c-59];
      else if (c < 151) s += reg_b[c-79];
    }

    if (t >= 79 && t < 151) {   // pose columns: add mfold contributions
      int p = t - 79, j = p / 3, o = p % 3;
      if (r < 57) {
        int jr = r / 3, d = r % 3;
        if (c_NEB1[j] == jr) s += mfold[(2*j+0)*12 + d*3 + o];
        if (c_NEB2[j] == jr) s += mfold[(2*j+1)*12 + d*3 + o];
      } else {
        s += mfold[(2*j+0)*12 + 9 + o] + mfold[(2*j+1)*12 + 9 + o];
      }
    }
    sbase[t] = s;
  }
  __syncthreads();

  float v0 = sbase[79], v1 = sbase[80], v2 = sbase[81];
  if (t < NCOL) {
    float s = sbase[t];
    if (t >= 79 && t < 151) {   // pred_pose = pose - pose[:, 0]
      int o = (t - 79) % 3;
      s -= (o == 0) ? v0 : ((o == 1) ? v1 : v2);
    }
    Cfull[r*NCOL + t] = s;
  }
}

// ---------------------------------------------------------------------------
// K3: out[b, 0:151] = x[b, 0:57] @ Cfull[0:57] + Cfull[57], scattered into the
// 5 output regions. Wave handles 4 rows; lane l owns cols (2l,2l+1) and
// (128+2l, 129+2l). Cfull staged in LDS.
// ---------------------------------------------------------------------------
__device__ __forceinline__ void store_col(float* __restrict__ out, int b, int c, float v) {
  if (c < 10)       out[SHAPE_OFF + b*10 + c]      = v;
  else if (c < 13)  out[CAM_OFF   + b*3  + (c-10)] = v;
  else if (c < 59)  out[PHI_OFF   + b*46 + (c-13)] = v;
  else if (c < 79)  out[LEAF_OFF  + b*20 + (c-59)] = v;
  else              out[POSE_OFF  + b*72 + (c-79)] = v;
}

__global__ __launch_bounds__(256) void k_main(
    const float* __restrict__ joints, const float* __restrict__ Cfull,
    float* __restrict__ out) {
  __shared__ float C[NROW * NCOL];   // 8816 floats = 35264 B
  for (int i = threadIdx.x; i < (NROW*NCOL)/4; i += 256)
    ((float4*)C)[i] = ((const float4*)Cfull)[i];
  __syncthreads();

  int w = __builtin_amdgcn_readfirstlane((int)(threadIdx.x >> 6));
  int l = (int)(threadIdx.x & 63);
  int b0 = blockIdx.x * 16 + w * 4;

  const float* x0 = joints + (size_t)b0 * 57;  // wave-uniform -> s_loads
  const float* x1 = x0 + 57;
  const float* x2 = x1 + 57;
  const float* x3 = x2 + 57;

  int lc = (l < 12) ? (2*l) : 22;  // clamp second-slot LDS addr in-bounds

  float acc[4][4] = {};
  #pragma unroll
  for (int r = 0; r < 58; ++r) {
    float2 p0 = *(const float2*)&C[r*NCOL + 2*l];
    float2 p1 = *(const float2*)&C[r*NCOL + 128 + lc];
    float xr;
    xr = (r < 57) ? x0[r] : 1.f;
    acc[0][0] += xr*p0.x; acc[0][1] += xr*p0.y; acc[0][2] += xr*p1.x; acc[0][3] += xr*p1.y;
    xr = (r < 57) ? x1[r] : 1.f;
    acc[1][0] += xr*p0.x; acc[1][1] += xr*p0.y; acc[1][2] += xr*p1.x; acc[1][3] += xr*p1.y;
    xr = (r < 57) ? x2[r] : 1.f;
    acc[2][0] += xr*p0.x; acc[2][1] += xr*p0.y; acc[2][2] += xr*p1.x; acc[2][3] += xr*p1.y;
    xr = (r < 57) ? x3[r] : 1.f;
    acc[3][0] += xr*p0.x; acc[3][1] += xr*p0.y; acc[3][2] += xr*p1.x; acc[3][3] += xr*p1.y;
  }

  #pragma unroll
  for (int i = 0; i < 4; ++i) {
    int b = b0 + i;
    store_col(out, b, 2*l,     acc[i][0]);
    store_col(out, b, 2*l + 1, acc[i][1]);
    if (l < 12) {
      store_col(out, b, 128 + 2*l, acc[i][2]);
      if (l < 11) store_col(out, b, 129 + 2*l, acc[i][3]);  // col 151 is pad
    }
  }
}

extern "C" void kernel_launch(void* const* d_in, const int* in_sizes, int n_in,
                              void* d_out, int out_size, void* d_ws, size_t ws_size,
                              hipStream_t stream) {
  const float* joints     = (const float*)d_in[0];
  const float* W_enc      = (const float*)d_in[1];
  const float* b_enc      = (const float*)d_in[2];
  const float* W_shape    = (const float*)d_in[3];
  const float* b_shape    = (const float*)d_in[4];
  const float* W_cam      = (const float*)d_in[5];
  const float* b_cam      = (const float*)d_in[6];
  const float* W_phi      = (const float*)d_in[7];
  const float* b_phi      = (const float*)d_in[8];
  const float* W_leaf     = (const float*)d_in[9];
  const float* b_leaf     = (const float*)d_in[10];
  const float* init_shape = (const float*)d_in[11];
  const float* init_cam   = (const float*)d_in[12];
  const float* L1_w       = (const float*)d_in[13];
  const float* L1_b       = (const float*)d_in[14];
  const float* L2_w       = (const float*)d_in[15];
  const float* L2_b       = (const float*)d_in[16];
  const float* Rf         = (const float*)d_in[17];
  const float* R1         = (const float*)d_in[18];
  const float* R2         = (const float*)d_in[19];
  const float* reg_b      = (const float*)d_in[20];

  float* partial = (float*)d_ws;                             // 58*16*152 f32
  float* Cfull   = partial + NROW*KC*NCOL;                   // 58*152 f32
  float* mfold   = Cfull + NROW*NCOL;                        // 48*12 f32
  float* outp    = (float*)d_out;

  hipLaunchKernelGGL(k_stage1, dim3(NCOLL_BLK + 48), dim3(256), 0, stream,
                     W_enc, b_enc, W_shape, W_cam, W_phi, W_leaf, Rf,
                     L1_w, L1_b, L2_w, L2_b, R1, R2, partial, mfold);
  hipLaunchKernelGGL(k_finalize, dim3(NROW), dim3(192), 0, stream,
                     partial, mfold, b_shape, b_cam, b_phi, b_leaf,
                     init_shape, init_cam, reg_b, Cfull);
  hipLaunchKernelGGL(k_main, dim3(512), dim3(256), 0, stream,
                     joints, Cfull, outp);
}